// Round 7
// baseline (342.038 us; speedup 1.0000x reference)
//
#include <hip/hip_runtime.h>

// Quantizer: N=65536 rows, D=512, V=512 codes, fp32 in/out.
// score[n,v] = dot(x[n],w[v]) - 0.5*c[v], c[v] = sum_rows w[r][v]^2 (column sums).
// out[n,:] = w[argmax_v score] (== np argmin of -2dot+c).
// R7: phase de-convoy. R5/R6 falsified occupancy/B-latency/B-BW theories
// (time pinned at ~130 across 2x occupancy and 2x B-traffic); remaining k1
// mass = memory phases (stage x-read + fused gather w-read/out-write) at 25%
// HBM. Split: k1 scores -> idx[] only (WRITE ~0); separate pure-streaming
// gather kernel (out = w[idx], 134 MB at high occupancy). Also fused
// prep_w+colsumsq (fp64 atomics, memset-zeroed) to cut aux time + 1 launch.
// fp16 score err rms ~0.009; EPS 0.18 -> ~1500 flagged rows exact-refined.

#define DIM   512
#define VOCAB 512
#define EPS_GAP 0.18f
#define RBATCH 8

typedef float f32x4 __attribute__((ext_vector_type(4)));
typedef _Float16 f16x8 __attribute__((ext_vector_type(8)));
typedef unsigned long long u64;

__device__ inline u64 packkey(float s, int v){
    unsigned u = __float_as_uint(s);
    u = (u & 0x80000000u) ? ~u : (u | 0x80000000u);   // orderable map
    return (((u64)u) << 32) | (unsigned)(~v);         // low word: bigger = smaller v
}
__device__ inline float keyscore(u64 k){
    unsigned e = (unsigned)(k >> 32);
    return __uint_as_float((e & 0x80000000u) ? (e & 0x7fffffffu) : ~e);
}
__device__ inline int keyv(u64 k){ return (int)(~(unsigned)(k & 0xffffffffu)); }
__device__ inline u64 umax64(u64 a, u64 b){ return a > b ? a : b; }
__device__ inline u64 umin64(u64 a, u64 b){ return a < b ? a : b; }

// ---- fused prep: w -> fp16 whc (fragment layout) + fp64 column-sum atomics ----
// grid 128 x 256; block handles 4 rows x 512 cols. Thread t owns cols {2t,2t+1}:
// float2 loads (512B/wave contiguous), ushort2 fragment stores, per-thread fp64
// partials over 4 rows -> 2 atomicAdd. cgd/cnt pre-zeroed by memset.
// frag(ch,quad,col): whc[ch*16384 + quad*4096 + col*8 ..+8] with (v=row,k=col):
// d = (k>>5)*16384 + ((k>>3)&3)*4096 + v*8 + (k&7)
__global__ void prep_fused(const float* __restrict__ w,
                           _Float16* __restrict__ whc,
                           double* __restrict__ cgd){
    const int t  = threadIdx.x;
    const int r0 = blockIdx.x * 4;
    const int c0 = t * 2;                     // even column
    double s0 = 0.0, s1 = 0.0;
    #pragma unroll
    for (int rr = 0; rr < 4; ++rr){
        const int row = r0 + rr;
        const float2 v = *(const float2*)(w + (long)row * VOCAB + c0);
        s0 += (double)v.x * (double)v.x;
        s1 += (double)v.y * (double)v.y;
        union { _Float16 h[2]; unsigned u; } cv;
        cv.h[0] = (_Float16)v.x;              // RNE v_cvt_f16_f32
        cv.h[1] = (_Float16)v.y;
        const int d = ((c0 >> 5) * 16384) + (((c0 >> 3) & 3) * 4096) + row * 8 + (c0 & 7);
        *(unsigned*)&whc[d] = cv.u;           // d even -> 4B aligned
    }
    atomicAdd(&cgd[c0],     s0);
    atomicAdd(&cgd[c0 + 1], s1);
}

// ---- k1: fp16 MFMA scores -> idx[] + near-tie flags (NO gather, WRITE ~0) ----
// block 256 thr = 4 waves; block tile 32 rows x 512 cols; grid 2048.
// wave tile: 32 rows x 128 cols (rt=2 x ct=8, 16x16x32 f16 MFMA, 64 acc regs).
// A staged in LDS once (32 rows x 512 k fp16, 32KB); B fragments direct from
// L2-hot whc. LDS ~33.5KB -> 4 blocks/CU; launch_bounds(256,4).
__launch_bounds__(256, 4)
__global__ void k1_scores(const float* __restrict__ x,
                          const _Float16* __restrict__ whc,
                          const double* __restrict__ cgd,
                          int* __restrict__ idx,
                          int* __restrict__ list,
                          unsigned* __restrict__ cnt){
    __shared__ __align__(16) _Float16 Ah[16384];  // [ch=16][quad=4][row=32][8]
    __shared__ u64 mergeK[32][4][2];

    const int t = threadIdx.x;
    const int lane = t & 63, wv = t >> 6, quad = lane >> 4, lm = lane & 15;
    const int cb = wv << 7;                 // wave col base (0,128,256,384)
    const long rbase = (long)blockIdx.x * 32;
    const float* xblk = x + rbase * DIM;

    // acc init = -0.5*c[col] (bias folded; all rows of a lane share its col)
    f32x4 acc[2][8];
    #pragma unroll
    for (int ct = 0; ct < 8; ++ct){
        const float bias = -0.5f * (float)cgd[cb + ct * 16 + lm];
        f32x4 z; z[0] = bias; z[1] = bias; z[2] = bias; z[3] = bias;
        acc[0][ct] = z; acc[1][ct] = z;
    }

    // stage A: 32 rows x 512 k fp32 -> fp16 fragment layout (one shot).
    // unroll 8: 8 float4 loads in flight for stage MLP.
    #pragma unroll 8
    for (int jj = 0; jj < 16; ++jj){
        const int j   = jj * 256 + t;                 // 0..4095 float4 slots
        const int row = (j >> 3) & 31;
        const int k4  = (j & 7) | ((j >> 8) << 3);    // 0..127
        const int kk  = k4 << 2;                      // 0..508, 4-aligned
        const float4 a4 = *(const float4*)(xblk + (long)row * DIM + kk);
        union { _Float16 h[4]; ushort4 u; } cv;
        cv.h[0] = (_Float16)a4.x;
        cv.h[1] = (_Float16)a4.y;
        cv.h[2] = (_Float16)a4.z;
        cv.h[3] = (_Float16)a4.w;
        const int d = (((kk >> 5) * 4 + ((kk >> 3) & 3)) * 32 + row) * 8 + (kk & 7);
        *(ushort4*)&Ah[d] = cv.u;
    }
    __syncthreads();

    // barrier-free inner loop over all 16 chunks
    for (int ch = 0; ch < 16; ++ch){
        // A frags from LDS: row = rt*16 + lm, k = quad*8 + j (verified R1/R5)
        f16x8 ah0 = *(const f16x8*)&Ah[((ch * 4 + quad) * 32 + lm) * 8];
        f16x8 ah1 = *(const f16x8*)&Ah[((ch * 4 + quad) * 32 + 16 + lm) * 8];
        // B frags direct from global (L2-hot, 16B/lane, 256B/quad contiguous)
        const _Float16* bb = whc + ch * 16384 + quad * 4096;
        #pragma unroll
        for (int ct = 0; ct < 8; ++ct){
            const f16x8 bh = *(const f16x8*)(bb + (cb + ct * 16 + lm) * 8);
            acc[0][ct] = __builtin_amdgcn_mfma_f32_16x16x32_f16(ah0, bh, acc[0][ct], 0, 0, 0);
            acc[1][ct] = __builtin_amdgcn_mfma_f32_16x16x32_f16(ah1, bh, acc[1][ct], 0, 0, 0);
        }
    }

    // epilogue: per-lane top-2 over its 8 cols, lm-merge (16 lanes = 128 cols)
    #pragma unroll
    for (int rt = 0; rt < 2; ++rt){
        #pragma unroll
        for (int reg = 0; reg < 4; ++reg){
            u64 b1 = 0, b2 = 0;
            #pragma unroll
            for (int ct = 0; ct < 8; ++ct){
                const u64 key = packkey(acc[rt][ct][reg], cb + ct * 16 + lm);
                if (key > b1){ b2 = b1; b1 = key; }
                else if (key > b2){ b2 = key; }
            }
            #pragma unroll
            for (int m = 1; m <= 8; m <<= 1){
                const u64 o1 = __shfl_xor(b1, m, 64);
                const u64 o2 = __shfl_xor(b2, m, 64);
                const u64 n1 = umax64(b1, o1);
                b2 = umax64(umin64(b1, o1), umax64(b2, o2));
                b1 = n1;
            }
            if (lm == 0){
                const int row = rt * 16 + quad * 4 + reg;   // 0..31
                mergeK[row][wv][0] = b1;
                mergeK[row][wv][1] = b2;
            }
        }
    }
    __syncthreads();
    if (t < 32){
        u64 p1 = mergeK[t][0][0], p2 = mergeK[t][0][1];
        #pragma unroll
        for (int i = 1; i < 4; ++i){
            const u64 q1 = mergeK[t][i][0], q2 = mergeK[t][i][1];
            const u64 n1 = umax64(p1, q1);
            p2 = umax64(umin64(p1, q1), umax64(p2, q2));
            p1 = n1;
        }
        idx[rbase + t] = keyv(p1);
        if (keyscore(p1) - keyscore(p2) < EPS_GAP){
            const unsigned p = atomicAdd(cnt, 1u);
            list[p] = (int)(rbase + t);
        }
    }
}

// ---- gather: out[n,:] = w[idx[n],:] -- pure streaming, high occupancy ----
// grid 2048 x 256; block covers 32 consecutive rows (16 iters x 2 rows).
__global__ void gather_rows(const float* __restrict__ w,
                            const int* __restrict__ idx,
                            float* __restrict__ out){
    const int t = threadIdx.x;
    #pragma unroll 4
    for (int g = 0; g < 16; ++g){
        const long flat = ((long)blockIdx.x * 16 + g) * 256 + t;  // float4 slot
        const int  row  = (int)(flat >> 7);
        const int  c4   = (int)(flat & 127);
        const int  vidx = idx[row];
        const float4 val = *(const float4*)(w + (long)vidx * DIM + c4 * 4);
        *(float4*)(out + flat * 4) = val;
    }
}

// ---- exact fp32 re-check + rewrite for flagged (near-tie) rows, BATCHED ----
__global__ void refine_rows(const float* __restrict__ x, const float* __restrict__ w,
                            const double* __restrict__ cgd, const int* __restrict__ list,
                            const unsigned* __restrict__ cnt, float* __restrict__ out){
    __shared__ __align__(16) float xs[RBATCH][DIM];
    __shared__ u64 wk[RBATCH][4];
    __shared__ int bestv_s[RBATCH];
    const int t = threadIdx.x;
    const int lane = t & 63, wvq = t >> 6;
    const int n = (int)*cnt;
    for (int base = blockIdx.x * RBATCH; base < n; base += gridDim.x * RBATCH){
        const int m = (n - base < RBATCH) ? (n - base) : RBATCH;
        __syncthreads();   // protect xs/bestv_s reuse across iterations
        for (int s = t; s < m * 128; s += 256){
            const int r = s >> 7, c = (s & 127) << 2;
            *(float4*)&xs[r][c] = *(const float4*)(x + (long)list[base + r] * DIM + c);
        }
        __syncthreads();
        u64 best[RBATCH];
        #pragma unroll
        for (int r = 0; r < RBATCH; ++r) best[r] = 0;
        #pragma unroll
        for (int vv = 0; vv < 2; ++vv){
            const int v = t + vv * 256;
            const float* wr = w + (long)v * DIM;
            float s[RBATCH];
            #pragma unroll
            for (int r = 0; r < RBATCH; ++r) s[r] = -0.5f * (float)cgd[v];
            for (int k = 0; k < DIM; k += 4){
                const float4 w4 = *(const float4*)(wr + k);
                #pragma unroll
                for (int r = 0; r < RBATCH; ++r){
                    const float4 x4 = *(const float4*)&xs[r][k];
                    s[r] = fmaf(w4.x, x4.x, s[r]);
                    s[r] = fmaf(w4.y, x4.y, s[r]);
                    s[r] = fmaf(w4.z, x4.z, s[r]);
                    s[r] = fmaf(w4.w, x4.w, s[r]);
                }
            }
            #pragma unroll
            for (int r = 0; r < RBATCH; ++r)
                best[r] = umax64(best[r], packkey(s[r], v));
        }
        #pragma unroll
        for (int r = 0; r < RBATCH; ++r){
            u64 b = best[r];
            #pragma unroll
            for (int mm = 1; mm <= 32; mm <<= 1) b = umax64(b, __shfl_xor(b, mm, 64));
            if (lane == 0) wk[r][wvq] = b;
        }
        __syncthreads();
        if (t < RBATCH){
            const u64 b = umax64(umax64(wk[t][0], wk[t][1]), umax64(wk[t][2], wk[t][3]));
            bestv_s[t] = keyv(b);
        }
        __syncthreads();
        for (int s = t; s < m * 128; s += 256){
            const int r = s >> 7, c = (s & 127) << 2;
            *(float4*)(out + (long)list[base + r] * DIM + c) =
                *(const float4*)(w + (long)bestv_s[r] * DIM + c);
        }
    }
}

// ---- fallback: round-1 fp32 kernel (self-contained, no ws) ----
__launch_bounds__(256)
__global__ void fallback_full(const float* __restrict__ x, const float* __restrict__ w,
                              float* __restrict__ out){
    __shared__ __align__(16) float As[16][68];
    __shared__ __align__(16) float Bs[16][VOCAB];
    __shared__ int   idx_sf[64];
    __shared__ float c_s[VOCAB];

    const int t  = threadIdx.x;
    const int tx = t & 31;
    const int ty = t >> 5;
    const long rbase = (long)blockIdx.x * 64;
    const float* xblk = x + rbase * DIM;

    for (int vv = t; vv < VOCAB; vv += 256){
        double s = 0.0;
        for (int i = 0; i < DIM; ++i){
            const float wvv = w[i * VOCAB + vv];
            s += (double)wvv * (double)wvv;
        }
        c_s[vv] = (float)s;
    }

    float acc[8][16];
    #pragma unroll
    for (int r = 0; r < 8; ++r)
        #pragma unroll
        for (int j = 0; j < 16; ++j) acc[r][j] = 0.0f;

    for (int k0 = 0; k0 < DIM; k0 += 16){
        __syncthreads();
        {
            const int r  = t >> 2;
            const int kq = (t & 3) << 2;
            const float4 a4 = *(const float4*)(xblk + (long)r * DIM + k0 + kq);
            As[kq + 0][r] = a4.x; As[kq + 1][r] = a4.y;
            As[kq + 2][r] = a4.z; As[kq + 3][r] = a4.w;
        }
        #pragma unroll
        for (int vb = 0; vb < 8; ++vb){
            const int v  = (t >> 2) + (vb << 6);
            const int kq = (t & 3) << 2;
            const float4 b4 = *(const float4*)(w + (long)v * DIM + k0 + kq);
            Bs[kq + 0][v] = b4.x; Bs[kq + 1][v] = b4.y;
            Bs[kq + 2][v] = b4.z; Bs[kq + 3][v] = b4.w;
        }
        __syncthreads();

        #pragma unroll
        for (int k = 0; k < 16; ++k){
            float a[8];
            const float4 a03 = *(const float4*)&As[k][ty * 8];
            const float4 a47 = *(const float4*)&As[k][ty * 8 + 4];
            a[0] = a03.x; a[1] = a03.y; a[2] = a03.z; a[3] = a03.w;
            a[4] = a47.x; a[5] = a47.y; a[6] = a47.z; a[7] = a47.w;
            float b[16];
            #pragma unroll
            for (int j = 0; j < 16; ++j) b[j] = Bs[k][tx + (j << 5)];
            #pragma unroll
            for (int r = 0; r < 8; ++r)
                #pragma unroll
                for (int j = 0; j < 16; ++j)
                    acc[r][j] = fmaf(a[r], b[j], acc[r][j]);
        }
    }

    #pragma unroll
    for (int r = 0; r < 8; ++r){
        float best = acc[r][0] - 0.5f * c_s[tx];
        int   bv   = tx;
        #pragma unroll
        for (int j = 1; j < 16; ++j){
            const float s = acc[r][j] - 0.5f * c_s[tx + (j << 5)];
            if (s > best){ best = s; bv = tx + (j << 5); }
        }
        unsigned u = __float_as_uint(best);
        u = (u & 0x80000000u) ? ~u : (u | 0x80000000u);
        u64 key = ((u64)u << 32) | (unsigned)(~(unsigned)bv);
        #pragma unroll
        for (int m = 1; m <= 16; m <<= 1){
            const u64 o = __shfl_xor(key, m, 64);
            if (o > key) key = o;
        }
        if (tx == 0) idx_sf[ty * 8 + r] = (int)(~(unsigned)(key & 0xFFFFFFFFull));
    }
    __syncthreads();

    for (int rr = 0; rr < 64; rr += 2){
        const int row  = rr + (t >> 7);
        const int col  = (t & 127) << 2;
        const int vidx = idx_sf[row];
        const float4 val = *(const float4*)(w + (long)vidx * DIM + col);
        *(float4*)(out + (rbase + row) * DIM + col) = val;
    }
}

extern "C" void kernel_launch(void* const* d_in, const int* in_sizes, int n_in,
                              void* d_out, int out_size, void* d_ws, size_t ws_size,
                              hipStream_t stream){
    const float* x = (const float*)d_in[0];
    const float* w = (const float*)d_in[1];
    float* out = (float*)d_out;
    const int rows = in_sizes[0] / DIM;        // 65536

    // ws layout (bytes)
    const size_t whc_off  = 0;
    const size_t cgd_off  = whc_off + (size_t)DIM * VOCAB * 2;   // 512KB fp16 w
    const size_t cnt_off  = cgd_off + (size_t)VOCAB * 8;         // 4KB fp64 c
    const size_t idx_off  = cnt_off + 64;
    const size_t list_off = idx_off + (size_t)rows * 4;
    const size_t need     = list_off + (size_t)rows * 4;

    if (ws_size >= need){
        _Float16* whc  = (_Float16*)((char*)d_ws + whc_off);
        double*   cgd  = (double*)((char*)d_ws + cgd_off);
        unsigned* cnt  = (unsigned*)((char*)d_ws + cnt_off);
        int*      idx  = (int*)((char*)d_ws + idx_off);
        int*      list = (int*)((char*)d_ws + list_off);

        // zero cgd (4KB) + cnt (adjacent 64B) in one tiny async memset
        hipMemsetAsync((char*)d_ws + cgd_off, 0, (size_t)VOCAB * 8 + 64, stream);
        prep_fused<<<VOCAB / 4, 256, 0, stream>>>(w, whc, cgd);
        k1_scores<<<rows / 32, 256, 0, stream>>>(x, whc, cgd, idx, list, cnt);
        gather_rows<<<rows / 32, 256, 0, stream>>>(w, idx, out);
        refine_rows<<<512, 256, 0, stream>>>(x, w, cgd, list, cnt, out);
    } else {
        fallback_full<<<rows / 64, 256, 0, stream>>>(x, w, out);
    }
}